// Round 1
// baseline (233.711 us; speedup 1.0000x reference)
//
#include <hip/hip_runtime.h>
#include <hip/hip_bf16.h>

using u16 = unsigned short;
using s16x8 = __attribute__((ext_vector_type(8))) short;   // 8 bf16 (4 VGPRs)
using f32x4 = __attribute__((ext_vector_type(4))) float;   // MFMA accum

__device__ __forceinline__ f32x4 mfma16(s16x8 a, s16x8 b, f32x4 c) {
    return __builtin_amdgcn_mfma_f32_16x16x32_bf16(a, b, c, 0, 0, 0);
}

__device__ __forceinline__ u16 f2bf(float f) {
    union { float f; unsigned u; } v; v.f = f;
    unsigned r = v.u + 0x7FFFu + ((v.u >> 16) & 1u);   // RNE
    return (u16)(r >> 16);
}

__device__ __forceinline__ unsigned pk2(u16 a, u16 b) {
    return (unsigned)a | ((unsigned)b << 16);
}

// ---------------------------------------------------------------------------
// 1) fp32 -> bf16 conversion of x and the 4 weight matrices (one launch).
// segment quad counts: x 524288 | Wqkv 49152 | out_w 16384 | ffn1 65536 | ffn2 32768
// ---------------------------------------------------------------------------
__global__ __launch_bounds__(256) void conv_kernel(
    const float* __restrict__ s0, const float* __restrict__ s1,
    const float* __restrict__ s2, const float* __restrict__ s3,
    const float* __restrict__ s4,
    u16* __restrict__ d0, u16* __restrict__ d1, u16* __restrict__ d2,
    u16* __restrict__ d3, u16* __restrict__ d4)
{
    int i = blockIdx.x * 256 + threadIdx.x;
    const float* s; u16* d; int off;
    if (i < 524288)      { s = s0; d = d0; off = i; }
    else if (i < 573440) { s = s1; d = d1; off = i - 524288; }
    else if (i < 589824) { s = s2; d = d2; off = i - 573440; }
    else if (i < 655360) { s = s3; d = d3; off = i - 589824; }
    else                 { s = s4; d = d4; off = i - 655360; }
    float4 f = ((const float4*)s)[off];
    ushort4 u;
    u.x = f2bf(f.x); u.y = f2bf(f.y); u.z = f2bf(f.z); u.w = f2bf(f.w);
    ((ushort4*)d)[off] = u;
}

// ---------------------------------------------------------------------------
// Generic bf16 MFMA GEMM: out[M][N] = A[M][K] * W[N][K]^T + bias (+resid)
// Tile 128x64, 4 waves (2x2), per-wave 64x32 via 16x16x32 MFMA, BK=64.
// A/B fragments both use k-map 8*(lane>>4)+j -> exact regardless of HW intra-k
// permutation (applied identically to both operands).
// OUTMODE: 0 = fp32 out, 1 = bf16 out. SPLIT: A = [A0 | A1] (256+256 cols).
// ---------------------------------------------------------------------------
template<int OUTMODE, bool SPLIT, bool RESID>
__global__ __launch_bounds__(256) void gemm_kernel(
    const u16* __restrict__ A0, const u16* __restrict__ A1,
    const u16* __restrict__ W, const float* __restrict__ bias,
    const float* __restrict__ resid, float* __restrict__ outf,
    u16* __restrict__ outb, int M, int N, int K)
{
    __shared__ u16 A_lds[128][72];   // +8 pad -> even bank coverage
    __shared__ u16 B_lds[64][72];
    const int tid = threadIdx.x;
    const int l = tid & 63, w = tid >> 6;
    const int lr = l & 15, lg = l >> 4;
    const int m0 = blockIdx.x * 128, n0 = blockIdx.y * 64;
    const int wm = (w >> 1) * 64, wn = (w & 1) * 32;

    f32x4 acc[4][2];
    #pragma unroll
    for (int i = 0; i < 4; ++i)
        #pragma unroll
        for (int j = 0; j < 2; ++j)
            acc[i][j] = (f32x4){0.f, 0.f, 0.f, 0.f};

    for (int k0 = 0; k0 < K; k0 += 64) {
        __syncthreads();
        const u16* Asrc; int lda;
        if (SPLIT) {
            lda = 256;
            Asrc = (k0 < 256) ? (A0 + k0) : (A1 + (k0 - 256));
        } else {
            lda = K; Asrc = A0 + k0;
        }
        #pragma unroll
        for (int i = 0; i < 4; ++i) {
            int c = tid + 256 * i;
            int row = c >> 3, cg = c & 7;
            *(uint4*)&A_lds[row][cg * 8] =
                *(const uint4*)(Asrc + (size_t)(m0 + row) * lda + cg * 8);
        }
        #pragma unroll
        for (int i = 0; i < 2; ++i) {
            int c = tid + 256 * i;
            int row = c >> 3, cg = c & 7;
            *(uint4*)&B_lds[row][cg * 8] =
                *(const uint4*)(W + (size_t)(n0 + row) * K + k0 + cg * 8);
        }
        __syncthreads();
        #pragma unroll
        for (int ks = 0; ks < 2; ++ks) {
            s16x8 af[4], bfr[2];
            #pragma unroll
            for (int ms = 0; ms < 4; ++ms)
                af[ms] = *(const s16x8*)&A_lds[wm + ms * 16 + lr][ks * 32 + lg * 8];
            #pragma unroll
            for (int ns = 0; ns < 2; ++ns)
                bfr[ns] = *(const s16x8*)&B_lds[wn + ns * 16 + lr][ks * 32 + lg * 8];
            #pragma unroll
            for (int ms = 0; ms < 4; ++ms)
                #pragma unroll
                for (int ns = 0; ns < 2; ++ns)
                    acc[ms][ns] = mfma16(af[ms], bfr[ns], acc[ms][ns]);
        }
    }
    // epilogue: D col = lane&15, row = (lane>>4)*4 + reg   [HW-verified]
    #pragma unroll
    for (int ms = 0; ms < 4; ++ms) {
        #pragma unroll
        for (int ns = 0; ns < 2; ++ns) {
            int cg = n0 + wn + ns * 16 + lr;
            float bv = bias[cg];
            #pragma unroll
            for (int r = 0; r < 4; ++r) {
                int rg = m0 + wm + ms * 16 + lg * 4 + r;
                float val = acc[ms][ns][r] + bv;
                if (RESID) val += resid[(size_t)rg * N + cg];
                if (OUTMODE == 0) outf[(size_t)rg * N + cg] = val;
                else              outb[(size_t)rg * N + cg] = f2bf(val);
            }
        }
    }
}

// ---------------------------------------------------------------------------
// 3) RoPE-style rotation + scatter. qkv fp32 [8192][768] interleaved (3c+sel).
// even c: rot = q[c]*cos[c] - q[c+1]*sin[c]; odd c: q[c]*cos[c] + q[c-1]*sin[c].
// q scaled by 0.125*log2(e) (softmax scale + exp2 folding).
// Outputs bf16 [bh][n][64].
// ---------------------------------------------------------------------------
__global__ __launch_bounds__(256) void rope_kernel(
    const float* __restrict__ qkv, const float* __restrict__ enc,
    u16* __restrict__ Qo, u16* __restrict__ Ko, u16* __restrict__ Vo)
{
    int idx = blockIdx.x * 256 + threadIdx.x;   // 8192*128 pairs
    int row = idx >> 7;                          // b*4096 + n
    int p = idx & 127;
    int c0 = p * 2;
    const float* base = qkv + (size_t)row * 768 + p * 6;
    float2 f01 = *(const float2*)(base + 0);
    float2 f23 = *(const float2*)(base + 2);
    float2 f45 = *(const float2*)(base + 4);
    float q0 = f01.x, k0 = f01.y, v0 = f23.x, q1 = f23.y, k1 = f45.x, v1 = f45.y;
    const float* cb = enc + (size_t)row * 256 + c0;
    float2 cosv = *(const float2*)cb;
    float2 sinv = *(const float2*)(cb + 2097152);   // sin plane offset 2*4096*256
    float qr0 = q0 * cosv.x - q1 * sinv.x;
    float qr1 = q1 * cosv.y + q0 * sinv.y;
    float kr0 = k0 * cosv.x - k1 * sinv.x;
    float kr1 = k1 * cosv.y + k0 * sinv.y;
    const float qs = 0.18033688011112042f;   // 0.125 * log2(e)
    qr0 *= qs; qr1 *= qs;
    int h = c0 >> 6, d = c0 & 63;
    int b = row >> 12, n = row & 4095;
    size_t o = (((size_t)(b * 4 + h)) * 4096 + n) * 64 + d;
    *(ushort2*)(Qo + o) = make_ushort2(f2bf(qr0), f2bf(qr1));
    *(ushort2*)(Ko + o) = make_ushort2(f2bf(kr0), f2bf(kr1));
    *(ushort2*)(Vo + o) = make_ushort2(f2bf(v0),  f2bf(v1));
}

// ---------------------------------------------------------------------------
// 4) V transpose per bh-slab: Vt[bh][d][n] <- V[bh][n][d]
// ---------------------------------------------------------------------------
__global__ __launch_bounds__(256) void transpose_v(
    const u16* __restrict__ V, u16* __restrict__ Vt)
{
    __shared__ u16 t[64][72];
    int bh = blockIdx.y, n0 = blockIdx.x * 64;
    int tid = threadIdx.x;
    #pragma unroll
    for (int i = 0; i < 2; ++i) {
        int c = tid + 256 * i;
        int r = c >> 3, cg = c & 7;
        *(uint4*)&t[r][cg * 8] =
            *(const uint4*)(V + ((size_t)bh * 4096 + n0 + r) * 64 + cg * 8);
    }
    __syncthreads();
    #pragma unroll
    for (int i = 0; i < 2; ++i) {
        int c = tid + 256 * i;
        int d = c >> 3, ng = c & 7;
        unsigned w0 = pk2(t[ng*8+0][d], t[ng*8+1][d]);
        unsigned w1 = pk2(t[ng*8+2][d], t[ng*8+3][d]);
        unsigned w2 = pk2(t[ng*8+4][d], t[ng*8+5][d]);
        unsigned w3 = pk2(t[ng*8+6][d], t[ng*8+7][d]);
        uint4 o4 = make_uint4(w0, w1, w2, w3);
        *(uint4*)(Vt + ((size_t)bh * 64 + d) * 4096 + n0 + ng * 8) = o4;
    }
}

// ---------------------------------------------------------------------------
// 5) Flash attention. Grid (64 q-tiles, 8 bh). 4 waves x 16 q-rows.
// q pre-scaled by 0.125*log2e -> softmax uses exp2. KV tile = 64, staged in LDS.
// P transposed through wave-private LDS (in-order LDS + lgkmcnt drain).
// ---------------------------------------------------------------------------
__global__ __launch_bounds__(256) void attn_kernel(
    const u16* __restrict__ Qp, const u16* __restrict__ Kp,
    const u16* __restrict__ Vtp, u16* __restrict__ ctx)
{
    __shared__ u16 K_lds[64][72];
    __shared__ u16 V_lds[64][72];          // Vt tile: [dv][kv]
    __shared__ u16 P_lds[4][16][72];       // wave-private
    const int tid = threadIdx.x;
    const int l = tid & 63, w = tid >> 6;
    const int lr = l & 15, lg = l >> 4;
    const int bh = blockIdx.y;
    const int n0 = blockIdx.x * 64 + w * 16;   // this wave's 16 q-rows

    const u16* Qb = Qp + ((size_t)bh * 4096 + n0) * 64;
    s16x8 qf0 = *(const s16x8*)(Qb + lr * 64 + lg * 8);
    s16x8 qf1 = *(const s16x8*)(Qb + lr * 64 + 32 + lg * 8);

    const u16* Kb = Kp + (size_t)bh * 4096 * 64;
    const u16* Vb = Vtp + (size_t)bh * 64 * 4096;

    f32x4 O[4];
    #pragma unroll
    for (int dv = 0; dv < 4; ++dv) O[dv] = (f32x4){0.f, 0.f, 0.f, 0.f};
    float m0r[4], s0r[4];
    #pragma unroll
    for (int r = 0; r < 4; ++r) { m0r[r] = -__builtin_inff(); s0r[r] = 0.f; }

    for (int kt = 0; kt < 64; ++kt) {
        __syncthreads();
        #pragma unroll
        for (int i = 0; i < 2; ++i) {
            int c = tid + 256 * i;
            int row = c >> 3, cg = c & 7;
            *(uint4*)&K_lds[row][cg * 8] =
                *(const uint4*)(Kb + ((size_t)(kt * 64 + row)) * 64 + cg * 8);
            *(uint4*)&V_lds[row][cg * 8] =
                *(const uint4*)(Vb + (size_t)row * 4096 + kt * 64 + cg * 8);
        }
        __syncthreads();

        // S = Q K^T  (S[v4]: q-rows x 16 kv; D row=q within 16, col=kv)
        f32x4 S[4];
        #pragma unroll
        for (int v4 = 0; v4 < 4; ++v4) {
            f32x4 z = (f32x4){0.f, 0.f, 0.f, 0.f};
            z = mfma16(qf0, *(const s16x8*)&K_lds[v4 * 16 + lr][lg * 8], z);
            z = mfma16(qf1, *(const s16x8*)&K_lds[v4 * 16 + lr][32 + lg * 8], z);
            S[v4] = z;
        }
        // online softmax (row reduce across the 16 lanes of each row-group)
        float mx[4];
        #pragma unroll
        for (int r = 0; r < 4; ++r)
            mx[r] = fmaxf(fmaxf(S[0][r], S[1][r]), fmaxf(S[2][r], S[3][r]));
        #pragma unroll
        for (int off = 8; off; off >>= 1)
            #pragma unroll
            for (int r = 0; r < 4; ++r)
                mx[r] = fmaxf(mx[r], __shfl_xor(mx[r], off, 16));
        float al[4], psum[4];
        #pragma unroll
        for (int r = 0; r < 4; ++r) {
            float mn = fmaxf(m0r[r], mx[r]);
            al[r] = exp2f(m0r[r] - mn);
            m0r[r] = mn;
            psum[r] = 0.f;
        }
        #pragma unroll
        for (int v4 = 0; v4 < 4; ++v4) {
            #pragma unroll
            for (int r = 0; r < 4; ++r) {
                float p = exp2f(S[v4][r] - m0r[r]);
                psum[r] += p;
                P_lds[w][lg * 4 + r][v4 * 16 + lr] = f2bf(p);
            }
        }
        #pragma unroll
        for (int off = 8; off; off >>= 1)
            #pragma unroll
            for (int r = 0; r < 4; ++r)
                psum[r] += __shfl_xor(psum[r], off, 16);
        #pragma unroll
        for (int r = 0; r < 4; ++r) s0r[r] = s0r[r] * al[r] + psum[r];
        #pragma unroll
        for (int dv = 0; dv < 4; ++dv)
            #pragma unroll
            for (int r = 0; r < 4; ++r)
                O[dv][r] *= al[r];

        // drain P writes before transposed re-read (wave-private, in-order LDS)
        asm volatile("s_waitcnt lgkmcnt(0)" ::: "memory");

        // O += P V  (A-frag from P_lds rows=q, B-frag from Vt tile)
        #pragma unroll
        for (int ks = 0; ks < 2; ++ks) {
            s16x8 pf = *(const s16x8*)&P_lds[w][lr][ks * 32 + lg * 8];
            #pragma unroll
            for (int dv = 0; dv < 4; ++dv)
                O[dv] = mfma16(pf,
                    *(const s16x8*)&V_lds[dv * 16 + lr][ks * 32 + lg * 8], O[dv]);
        }
    }

    int b = bh >> 2, h = bh & 3;
    float inv[4];
    #pragma unroll
    for (int r = 0; r < 4; ++r) inv[r] = 1.f / s0r[r];
    u16* cbase = ctx + ((size_t)b * 4096) * 256;
    #pragma unroll
    for (int dv = 0; dv < 4; ++dv)
        #pragma unroll
        for (int r = 0; r < 4; ++r) {
            int n = n0 + lg * 4 + r;
            cbase[(size_t)n * 256 + h * 64 + dv * 16 + lr] = f2bf(O[dv][r] * inv[r]);
        }
}

// ---------------------------------------------------------------------------
// 8) LayerNorm(512) + exact GELU, wave per row, bf16 out.
// ---------------------------------------------------------------------------
__global__ __launch_bounds__(256) void ln_gelu_kernel(
    const float* __restrict__ y, const float* __restrict__ g,
    const float* __restrict__ bta, u16* __restrict__ o)
{
    int row = blockIdx.x * 4 + (threadIdx.x >> 6);
    int l = threadIdx.x & 63;
    const float* yr = y + (size_t)row * 512 + l * 8;
    float4 va = *(const float4*)yr;
    float4 vb = *(const float4*)(yr + 4);
    float v[8] = {va.x, va.y, va.z, va.w, vb.x, vb.y, vb.z, vb.w};
    float s = 0.f;
    #pragma unroll
    for (int j = 0; j < 8; ++j) s += v[j];
    #pragma unroll
    for (int off = 32; off; off >>= 1) s += __shfl_xor(s, off, 64);
    float mu = s * (1.f / 512.f);
    float q = 0.f;
    #pragma unroll
    for (int j = 0; j < 8; ++j) { float t = v[j] - mu; q += t * t; }
    #pragma unroll
    for (int off = 32; off; off >>= 1) q += __shfl_xor(q, off, 64);
    float rs = rsqrtf(q * (1.f / 512.f) + 1e-5f);
    u16 u[8];
    #pragma unroll
    for (int j = 0; j < 8; ++j) {
        float t = (v[j] - mu) * rs * g[l * 8 + j] + bta[l * 8 + j];
        t = t * 0.5f * (1.f + erff(t * 0.70710678118654752f));
        u[j] = f2bf(t);
    }
    uint4 o4 = make_uint4(pk2(u[0], u[1]), pk2(u[2], u[3]),
                          pk2(u[4], u[5]), pk2(u[6], u[7]));
    *(uint4*)(o + (size_t)row * 512 + l * 8) = o4;
}

// ---------------------------------------------------------------------------
extern "C" void kernel_launch(void* const* d_in, const int* in_sizes, int n_in,
                              void* d_out, int out_size, void* d_ws, size_t ws_size,
                              hipStream_t stream) {
    (void)in_sizes; (void)n_in; (void)out_size; (void)ws_size;
    const float* x    = (const float*)d_in[0];
    const float* enc  = (const float*)d_in[1];
    const float* wqkv = (const float*)d_in[2];
    const float* bqkv = (const float*)d_in[3];
    const float* wout = (const float*)d_in[4];
    const float* bout = (const float*)d_in[5];
    const float* w1   = (const float*)d_in[6];
    const float* b1   = (const float*)d_in[7];
    const float* lng  = (const float*)d_in[8];
    const float* lnb  = (const float*)d_in[9];
    const float* w2   = (const float*)d_in[10];
    const float* b2   = (const float*)d_in[11];
    float* out = (float*)d_out;
    char* ws = (char*)d_ws;

    u16*   xb    = (u16*)(ws + 0);              // 4 MB   bf16 x [8192][256]
    u16*   wqkvb = (u16*)(ws + 4194304);        // 384 KB
    u16*   woutb = (u16*)(ws + 4587520);        // 128 KB
    u16*   w1b   = (u16*)(ws + 4718592);        // 512 KB
    u16*   w2b   = (u16*)(ws + 5242880);        // 256 KB
    float* qkvf  = (float*)(ws + 5505024);      // 24 MB  fp32 qkv [8192][768]
    float* y1    = qkvf;                        // reuse (16 MB) after rope
    u16*   q     = (u16*)(ws + 30670848);       // 4 MB  [bh][n][64]
    u16*   k     = (u16*)(ws + 34865152);       // 4 MB
    u16*   v     = (u16*)(ws + 39059456);       // 4 MB
    u16*   vt    = (u16*)(ws + 43253760);       // 4 MB  [bh][64][n]
    u16*   ybf   = q;                           // reuse q+k (8 MB) after attn
    u16*   ctx   = (u16*)(ws + 47448064);       // 4 MB
    u16*   msg   = (u16*)(ws + 51642368);       // 4 MB

    conv_kernel<<<2688, 256, 0, stream>>>(x, wqkv, wout, w1, w2,
                                          xb, wqkvb, woutb, w1b, w2b);
    // qkv = x @ Wqkv^T + b  (fp32 out)
    gemm_kernel<0, false, false><<<dim3(64, 12), 256, 0, stream>>>(
        xb, nullptr, wqkvb, bqkv, nullptr, qkvf, nullptr, 8192, 768, 256);
    rope_kernel<<<4096, 256, 0, stream>>>(qkvf, enc, q, k, v);
    transpose_v<<<dim3(64, 8), 256, 0, stream>>>(v, vt);
    attn_kernel<<<dim3(64, 8), 256, 0, stream>>>(q, k, vt, ctx);
    // message = ctx @ out_w^T + out_b  (bf16 out)
    gemm_kernel<1, false, false><<<dim3(64, 4), 256, 0, stream>>>(
        ctx, nullptr, woutb, bout, nullptr, nullptr, msg, 8192, 256, 256);
    // y1 = [x | message] @ ffn1^T + b1  (fp32 out)
    gemm_kernel<0, true, false><<<dim3(64, 8), 256, 0, stream>>>(
        xb, msg, w1b, b1, nullptr, y1, nullptr, 8192, 512, 512);
    ln_gelu_kernel<<<2048, 256, 0, stream>>>(y1, lng, lnb, ybf);
    // out = x + ybf @ ffn2^T + b2  (fp32 out, residual)
    gemm_kernel<0, false, true><<<dim3(64, 4), 256, 0, stream>>>(
        ybf, nullptr, w2b, b2, x, out, nullptr, 8192, 256, 512);
}

// Round 2
// 169.208 us; speedup vs baseline: 1.3812x; 1.3812x over previous
//
#include <hip/hip_runtime.h>
#include <hip/hip_bf16.h>

using u16 = unsigned short;
using s16x4 = __attribute__((ext_vector_type(4))) short;   // 4 bf16
using s16x8 = __attribute__((ext_vector_type(8))) short;   // 8 bf16 (4 VGPRs)
using f32x4 = __attribute__((ext_vector_type(4))) float;   // MFMA accum

__device__ __forceinline__ f32x4 mfma16(s16x8 a, s16x8 b, f32x4 c) {
    return __builtin_amdgcn_mfma_f32_16x16x32_bf16(a, b, c, 0, 0, 0);
}

__device__ __forceinline__ u16 f2bf(float f) {
    union { float f; unsigned u; } v; v.f = f;
    unsigned r = v.u + 0x7FFFu + ((v.u >> 16) & 1u);   // RNE
    return (u16)(r >> 16);
}

__device__ __forceinline__ unsigned pk2(u16 a, u16 b) {
    return (unsigned)a | ((unsigned)b << 16);
}

// ---------------------------------------------------------------------------
// 1) fp32 -> bf16 conversion of x and the 4 weight matrices (one launch).
// ---------------------------------------------------------------------------
__global__ __launch_bounds__(256) void conv_kernel(
    const float* __restrict__ s0, const float* __restrict__ s1,
    const float* __restrict__ s2, const float* __restrict__ s3,
    const float* __restrict__ s4,
    u16* __restrict__ d0, u16* __restrict__ d1, u16* __restrict__ d2,
    u16* __restrict__ d3, u16* __restrict__ d4)
{
    int i = blockIdx.x * 256 + threadIdx.x;
    const float* s; u16* d; int off;
    if (i < 524288)      { s = s0; d = d0; off = i; }
    else if (i < 573440) { s = s1; d = d1; off = i - 524288; }
    else if (i < 589824) { s = s2; d = d2; off = i - 573440; }
    else if (i < 655360) { s = s3; d = d3; off = i - 589824; }
    else                 { s = s4; d = d4; off = i - 655360; }
    float4 f = ((const float4*)s)[off];
    ushort4 u;
    u.x = f2bf(f.x); u.y = f2bf(f.y); u.z = f2bf(f.z); u.w = f2bf(f.w);
    ((ushort4*)d)[off] = u;
}

// ---------------------------------------------------------------------------
// Generic bf16 MFMA GEMM: out[M][N] = A[M][K] * W[N][K]^T + bias (+resid)
// ---------------------------------------------------------------------------
template<int OUTMODE, bool SPLIT, bool RESID>
__global__ __launch_bounds__(256) void gemm_kernel(
    const u16* __restrict__ A0, const u16* __restrict__ A1,
    const u16* __restrict__ W, const float* __restrict__ bias,
    const float* __restrict__ resid, float* __restrict__ outf,
    u16* __restrict__ outb, int M, int N, int K)
{
    __shared__ u16 A_lds[128][72];
    __shared__ u16 B_lds[64][72];
    const int tid = threadIdx.x;
    const int l = tid & 63, w = tid >> 6;
    const int lr = l & 15, lg = l >> 4;
    const int m0 = blockIdx.x * 128, n0 = blockIdx.y * 64;
    const int wm = (w >> 1) * 64, wn = (w & 1) * 32;

    f32x4 acc[4][2];
    #pragma unroll
    for (int i = 0; i < 4; ++i)
        #pragma unroll
        for (int j = 0; j < 2; ++j)
            acc[i][j] = (f32x4){0.f, 0.f, 0.f, 0.f};

    for (int k0 = 0; k0 < K; k0 += 64) {
        __syncthreads();
        const u16* Asrc; int lda;
        if (SPLIT) {
            lda = 256;
            Asrc = (k0 < 256) ? (A0 + k0) : (A1 + (k0 - 256));
        } else {
            lda = K; Asrc = A0 + k0;
        }
        #pragma unroll
        for (int i = 0; i < 4; ++i) {
            int c = tid + 256 * i;
            int row = c >> 3, cg = c & 7;
            *(uint4*)&A_lds[row][cg * 8] =
                *(const uint4*)(Asrc + (size_t)(m0 + row) * lda + cg * 8);
        }
        #pragma unroll
        for (int i = 0; i < 2; ++i) {
            int c = tid + 256 * i;
            int row = c >> 3, cg = c & 7;
            *(uint4*)&B_lds[row][cg * 8] =
                *(const uint4*)(W + (size_t)(n0 + row) * K + k0 + cg * 8);
        }
        __syncthreads();
        #pragma unroll
        for (int ks = 0; ks < 2; ++ks) {
            s16x8 af[4], bfr[2];
            #pragma unroll
            for (int ms = 0; ms < 4; ++ms)
                af[ms] = *(const s16x8*)&A_lds[wm + ms * 16 + lr][ks * 32 + lg * 8];
            #pragma unroll
            for (int ns = 0; ns < 2; ++ns)
                bfr[ns] = *(const s16x8*)&B_lds[wn + ns * 16 + lr][ks * 32 + lg * 8];
            #pragma unroll
            for (int ms = 0; ms < 4; ++ms)
                #pragma unroll
                for (int ns = 0; ns < 2; ++ns)
                    acc[ms][ns] = mfma16(af[ms], bfr[ns], acc[ms][ns]);
        }
    }
    #pragma unroll
    for (int ms = 0; ms < 4; ++ms) {
        #pragma unroll
        for (int ns = 0; ns < 2; ++ns) {
            int cg = n0 + wn + ns * 16 + lr;
            float bv = bias[cg];
            #pragma unroll
            for (int r = 0; r < 4; ++r) {
                int rg = m0 + wm + ms * 16 + lg * 4 + r;
                float val = acc[ms][ns][r] + bv;
                if (RESID) val += resid[(size_t)rg * N + cg];
                if (OUTMODE == 0) outf[(size_t)rg * N + cg] = val;
                else              outb[(size_t)rg * N + cg] = f2bf(val);
            }
        }
    }
}

// ---------------------------------------------------------------------------
// 3) RoPE-style rotation + scatter. q scaled by 0.125*log2(e).
// ---------------------------------------------------------------------------
__global__ __launch_bounds__(256) void rope_kernel(
    const float* __restrict__ qkv, const float* __restrict__ enc,
    u16* __restrict__ Qo, u16* __restrict__ Ko, u16* __restrict__ Vo)
{
    int idx = blockIdx.x * 256 + threadIdx.x;
    int row = idx >> 7;
    int p = idx & 127;
    int c0 = p * 2;
    const float* base = qkv + (size_t)row * 768 + p * 6;
    float2 f01 = *(const float2*)(base + 0);
    float2 f23 = *(const float2*)(base + 2);
    float2 f45 = *(const float2*)(base + 4);
    float q0 = f01.x, k0 = f01.y, v0 = f23.x, q1 = f23.y, k1 = f45.x, v1 = f45.y;
    const float* cb = enc + (size_t)row * 256 + c0;
    float2 cosv = *(const float2*)cb;
    float2 sinv = *(const float2*)(cb + 2097152);
    float qr0 = q0 * cosv.x - q1 * sinv.x;
    float qr1 = q1 * cosv.y + q0 * sinv.y;
    float kr0 = k0 * cosv.x - k1 * sinv.x;
    float kr1 = k1 * cosv.y + k0 * sinv.y;
    const float qs = 0.18033688011112042f;   // 0.125 * log2(e)
    qr0 *= qs; qr1 *= qs;
    int h = c0 >> 6, d = c0 & 63;
    int b = row >> 12, n = row & 4095;
    size_t o = (((size_t)(b * 4 + h)) * 4096 + n) * 64 + d;
    *(ushort2*)(Qo + o) = make_ushort2(f2bf(qr0), f2bf(qr1));
    *(ushort2*)(Ko + o) = make_ushort2(f2bf(kr0), f2bf(kr1));
    *(ushort2*)(Vo + o) = make_ushort2(f2bf(v0),  f2bf(v1));
}

// ---------------------------------------------------------------------------
// 4) V transpose per bh-slab: Vt[bh][d][n] <- V[bh][n][d]
// ---------------------------------------------------------------------------
__global__ __launch_bounds__(256) void transpose_v(
    const u16* __restrict__ V, u16* __restrict__ Vt)
{
    __shared__ u16 t[64][72];
    int bh = blockIdx.y, n0 = blockIdx.x * 64;
    int tid = threadIdx.x;
    #pragma unroll
    for (int i = 0; i < 2; ++i) {
        int c = tid + 256 * i;
        int r = c >> 3, cg = c & 7;
        *(uint4*)&t[r][cg * 8] =
            *(const uint4*)(V + ((size_t)bh * 4096 + n0 + r) * 64 + cg * 8);
    }
    __syncthreads();
    #pragma unroll
    for (int i = 0; i < 2; ++i) {
        int c = tid + 256 * i;
        int d = c >> 3, ng = c & 7;
        unsigned w0 = pk2(t[ng*8+0][d], t[ng*8+1][d]);
        unsigned w1 = pk2(t[ng*8+2][d], t[ng*8+3][d]);
        unsigned w2 = pk2(t[ng*8+4][d], t[ng*8+5][d]);
        unsigned w3 = pk2(t[ng*8+6][d], t[ng*8+7][d]);
        uint4 o4 = make_uint4(w0, w1, w2, w3);
        *(uint4*)(Vt + ((size_t)bh * 64 + d) * 4096 + n0 + ng * 8) = o4;
    }
}

// ---------------------------------------------------------------------------
// 5) Flash attention, kv-split x2, swapped QK^T (P lane-local), defer-max.
// Grid (64 q-tiles, 8 bh, 2 z). 4 waves x 16 q-rows. KVBLK=64, 32 kt per z.
// S^T = mfma(K, Q): lane (lg,lr) holds S[q=lr][kv=16*v4+4*lg+r].
// PV uses k-map pi(lg,j) = 32*kb + 16*(j>>2) + 4*lg + (j&3) on BOTH operands
// -> P feeds PV's A-frag directly from registers; V B-frag = 2x ds_read_b64.
// Outputs unnormalized O (fp32) + per-row (m, s); combine_kernel merges z.
// ---------------------------------------------------------------------------
__global__ __launch_bounds__(256) void attn_kernel(
    const u16* __restrict__ Qp, const u16* __restrict__ Kp,
    const u16* __restrict__ Vtp, float* __restrict__ Opart,
    float2* __restrict__ MSpart)
{
    __shared__ u16 K_lds[64][72];
    __shared__ u16 V_lds[64][72];          // Vt tile: [d][kv]
    const int tid = threadIdx.x;
    const int l = tid & 63, w = tid >> 6;
    const int lr = l & 15, lg = l >> 4;
    const int bh = blockIdx.y, z = blockIdx.z;
    const int n0 = blockIdx.x * 64 + w * 16;

    const u16* Qb = Qp + ((size_t)bh * 4096 + n0) * 64;
    s16x8 qf0 = *(const s16x8*)(Qb + lr * 64 + lg * 8);
    s16x8 qf1 = *(const s16x8*)(Qb + lr * 64 + 32 + lg * 8);

    const u16* Kb = Kp + (size_t)bh * 4096 * 64 + (size_t)z * 2048 * 64;
    const u16* Vb = Vtp + (size_t)bh * 64 * 4096 + z * 2048;

    const int r0 = tid >> 3, cg = tid & 7;   // staging: rows r0, r0+32; col grp cg

    uint4 kreg0, kreg1, vreg0, vreg1;
    kreg0 = *(const uint4*)(Kb + (size_t)r0 * 64 + cg * 8);
    kreg1 = *(const uint4*)(Kb + (size_t)(r0 + 32) * 64 + cg * 8);
    vreg0 = *(const uint4*)(Vb + (size_t)r0 * 4096 + cg * 8);
    vreg1 = *(const uint4*)(Vb + (size_t)(r0 + 32) * 4096 + cg * 8);

    f32x4 O[4];
    #pragma unroll
    for (int dv = 0; dv < 4; ++dv) O[dv] = (f32x4){0.f, 0.f, 0.f, 0.f};
    float m = -__builtin_inff(), s0 = 0.f;

    for (int kt = 0; kt < 32; ++kt) {
        __syncthreads();   // all waves done reading LDS of previous tile
        *(uint4*)&K_lds[r0][cg * 8]      = kreg0;
        *(uint4*)&K_lds[r0 + 32][cg * 8] = kreg1;
        *(uint4*)&V_lds[r0][cg * 8]      = vreg0;
        *(uint4*)&V_lds[r0 + 32][cg * 8] = vreg1;
        if (kt + 1 < 32) {   // prefetch next tile; latency hides under compute
            const u16* Kt = Kb + (size_t)(kt + 1) * 64 * 64;
            const u16* Vn = Vb + (size_t)(kt + 1) * 64;
            kreg0 = *(const uint4*)(Kt + (size_t)r0 * 64 + cg * 8);
            kreg1 = *(const uint4*)(Kt + (size_t)(r0 + 32) * 64 + cg * 8);
            vreg0 = *(const uint4*)(Vn + (size_t)r0 * 4096 + cg * 8);
            vreg1 = *(const uint4*)(Vn + (size_t)(r0 + 32) * 4096 + cg * 8);
        }
        __syncthreads();   // tile ready

        // S^T = K Q^T : per v4, two mfmas over d halves
        f32x4 S[4];
        #pragma unroll
        for (int v4 = 0; v4 < 4; ++v4) {
            s16x8 kf0 = *(const s16x8*)&K_lds[v4 * 16 + lr][lg * 8];
            s16x8 kf1 = *(const s16x8*)&K_lds[v4 * 16 + lr][32 + lg * 8];
            f32x4 zz = (f32x4){0.f, 0.f, 0.f, 0.f};
            zz = mfma16(kf0, qf0, zz);
            zz = mfma16(kf1, qf1, zz);
            S[v4] = zz;
        }

        // row max (q = lr is lane-local; kv spread over regs + lg groups)
        float pmax = S[0][0];
        #pragma unroll
        for (int v4 = 0; v4 < 4; ++v4)
            #pragma unroll
            for (int r = 0; r < 4; ++r)
                pmax = fmaxf(pmax, S[v4][r]);
        pmax = fmaxf(pmax, __shfl_xor(pmax, 16));
        pmax = fmaxf(pmax, __shfl_xor(pmax, 32));

        // defer-max: only rescale when max grew past threshold (P <= 2^8)
        if (!__all(pmax <= m + 8.f)) {
            float mnew = fmaxf(m, pmax);
            float al = exp2f(m - mnew);
            m = mnew;
            float alq[4];
            #pragma unroll
            for (int r = 0; r < 4; ++r)
                alq[r] = __shfl(al, (l & 48) | (4 * lg + r));
            s0 *= al;
            #pragma unroll
            for (int dv = 0; dv < 4; ++dv)
                #pragma unroll
                for (int r = 0; r < 4; ++r)
                    O[dv][r] *= alq[r];
        }

        float p[4][4];
        float psum = 0.f;
        #pragma unroll
        for (int v4 = 0; v4 < 4; ++v4)
            #pragma unroll
            for (int r = 0; r < 4; ++r) {
                float pv = exp2f(S[v4][r] - m);
                p[v4][r] = pv;
                psum += pv;
            }
        psum += __shfl_xor(psum, 16);
        psum += __shfl_xor(psum, 32);
        s0 += psum;

        // pack P into PV A-frags (slot j: v4 = 2*kb + (j>>2), r = j&3)
        s16x8 pa[2];
        #pragma unroll
        for (int kb = 0; kb < 2; ++kb) {
            union { unsigned u[4]; s16x8 v; } pu;
            pu.u[0] = pk2(f2bf(p[2*kb][0]),   f2bf(p[2*kb][1]));
            pu.u[1] = pk2(f2bf(p[2*kb][2]),   f2bf(p[2*kb][3]));
            pu.u[2] = pk2(f2bf(p[2*kb+1][0]), f2bf(p[2*kb+1][1]));
            pu.u[3] = pk2(f2bf(p[2*kb+1][2]), f2bf(p[2*kb+1][3]));
            pa[kb] = pu.v;
        }

        // O += P V : B-frag V[kv=pi(lg,j)][d=16*dv+lr] via two b64 reads
        #pragma unroll
        for (int dv = 0; dv < 4; ++dv)
            #pragma unroll
            for (int kb = 0; kb < 2; ++kb) {
                const u16* vp = &V_lds[16 * dv + lr][32 * kb + 4 * lg];
                s16x4 va  = *(const s16x4*)vp;
                s16x4 vb4 = *(const s16x4*)(vp + 16);
                s16x8 vf = __builtin_shufflevector(va, vb4, 0,1,2,3,4,5,6,7);
                O[dv] = mfma16(pa[kb], vf, O[dv]);
            }
    }

    // epilogue: unnormalized O + (m, s) per q-row; combine normalizes
    float* Ob = Opart + ((size_t)(z * 8 + bh) * 4096 + n0) * 64;
    #pragma unroll
    for (int dv = 0; dv < 4; ++dv)
        #pragma unroll
        for (int r = 0; r < 4; ++r)
            Ob[(size_t)(4 * lg + r) * 64 + 16 * dv + lr] = O[dv][r];
    if (lg == 0) {
        float2 ms; ms.x = m; ms.y = s0;
        MSpart[(size_t)(z * 8 + bh) * 4096 + n0 + lr] = ms;
    }
}

// ---------------------------------------------------------------------------
// 5b) Combine the two kv-split partials -> ctx (bf16 [b][n][256])
// ---------------------------------------------------------------------------
__global__ __launch_bounds__(256) void combine_kernel(
    const float* __restrict__ Opart, const float2* __restrict__ MSpart,
    u16* __restrict__ ctx)
{
    int idx = blockIdx.x * 256 + threadIdx.x;    // 262144 = 32768 rows * 8 dc
    int rr = idx >> 3;            // bh*4096 + n
    int dc = (idx & 7) * 8;
    float2 ms0 = MSpart[rr];
    float2 ms1 = MSpart[32768 + rr];
    float mm = fmaxf(ms0.x, ms1.x);
    float w0 = exp2f(ms0.x - mm), w1 = exp2f(ms1.x - mm);
    float inv = 1.f / (ms0.y * w0 + ms1.y * w1);
    w0 *= inv; w1 *= inv;
    const float* O0 = Opart + (size_t)rr * 64 + dc;
    const float* O1 = O0 + (size_t)32768 * 64;
    float4 a0 = *(const float4*)O0;
    float4 a1 = *(const float4*)(O0 + 4);
    float4 b0 = *(const float4*)O1;
    float4 b1 = *(const float4*)(O1 + 4);
    u16 u[8];
    u[0] = f2bf(a0.x * w0 + b0.x * w1);
    u[1] = f2bf(a0.y * w0 + b0.y * w1);
    u[2] = f2bf(a0.z * w0 + b0.z * w1);
    u[3] = f2bf(a0.w * w0 + b0.w * w1);
    u[4] = f2bf(a1.x * w0 + b1.x * w1);
    u[5] = f2bf(a1.y * w0 + b1.y * w1);
    u[6] = f2bf(a1.z * w0 + b1.z * w1);
    u[7] = f2bf(a1.w * w0 + b1.w * w1);
    int bh = rr >> 12, n = rr & 4095;
    int b = bh >> 2, h = bh & 3;
    uint4 o4 = make_uint4(pk2(u[0], u[1]), pk2(u[2], u[3]),
                          pk2(u[4], u[5]), pk2(u[6], u[7]));
    *(uint4*)(ctx + ((size_t)(b * 4096 + n)) * 256 + h * 64 + dc) = o4;
}

// ---------------------------------------------------------------------------
// 8) LayerNorm(512) + exact GELU, wave per row, bf16 out.
// ---------------------------------------------------------------------------
__global__ __launch_bounds__(256) void ln_gelu_kernel(
    const float* __restrict__ y, const float* __restrict__ g,
    const float* __restrict__ bta, u16* __restrict__ o)
{
    int row = blockIdx.x * 4 + (threadIdx.x >> 6);
    int l = threadIdx.x & 63;
    const float* yr = y + (size_t)row * 512 + l * 8;
    float4 va = *(const float4*)yr;
    float4 vb = *(const float4*)(yr + 4);
    float v[8] = {va.x, va.y, va.z, va.w, vb.x, vb.y, vb.z, vb.w};
    float s = 0.f;
    #pragma unroll
    for (int j = 0; j < 8; ++j) s += v[j];
    #pragma unroll
    for (int off = 32; off; off >>= 1) s += __shfl_xor(s, off, 64);
    float mu = s * (1.f / 512.f);
    float q = 0.f;
    #pragma unroll
    for (int j = 0; j < 8; ++j) { float t = v[j] - mu; q += t * t; }
    #pragma unroll
    for (int off = 32; off; off >>= 1) q += __shfl_xor(q, off, 64);
    float rs = rsqrtf(q * (1.f / 512.f) + 1e-5f);
    u16 u[8];
    #pragma unroll
    for (int j = 0; j < 8; ++j) {
        float t = (v[j] - mu) * rs * g[l * 8 + j] + bta[l * 8 + j];
        t = t * 0.5f * (1.f + erff(t * 0.70710678118654752f));
        u[j] = f2bf(t);
    }
    uint4 o4 = make_uint4(pk2(u[0], u[1]), pk2(u[2], u[3]),
                          pk2(u[4], u[5]), pk2(u[6], u[7]));
    *(uint4*)(o + (size_t)row * 512 + l * 8) = o4;
}

// ---------------------------------------------------------------------------
extern "C" void kernel_launch(void* const* d_in, const int* in_sizes, int n_in,
                              void* d_out, int out_size, void* d_ws, size_t ws_size,
                              hipStream_t stream) {
    (void)in_sizes; (void)n_in; (void)out_size; (void)ws_size;
    const float* x    = (const float*)d_in[0];
    const float* enc  = (const float*)d_in[1];
    const float* wqkv = (const float*)d_in[2];
    const float* bqkv = (const float*)d_in[3];
    const float* wout = (const float*)d_in[4];
    const float* bout = (const float*)d_in[5];
    const float* w1   = (const float*)d_in[6];
    const float* b1   = (const float*)d_in[7];
    const float* lng  = (const float*)d_in[8];
    const float* lnb  = (const float*)d_in[9];
    const float* w2   = (const float*)d_in[10];
    const float* b2   = (const float*)d_in[11];
    float* out = (float*)d_out;
    char* ws = (char*)d_ws;

    u16*   xb    = (u16*)(ws + 0);              // 4 MB   bf16 x [8192][256]
    u16*   wqkvb = (u16*)(ws + 4194304);        // 384 KB
    u16*   woutb = (u16*)(ws + 4587520);        // 128 KB
    u16*   w1b   = (u16*)(ws + 4718592);        // 512 KB
    u16*   w2b   = (u16*)(ws + 5242880);        // 256 KB
    float* qkvf  = (float*)(ws + 5505024);      // 24 MB  fp32 qkv [8192][768]
    float* y1    = qkvf;                        // reuse (16 MB) after combine
    float* Opart = qkvf;                        // reuse (16 MB) after rope
    float2* MSpart = (float2*)(ws + 22282240);  // 512 KB (within qkv region)
    u16*   q     = (u16*)(ws + 30670848);       // 4 MB  [bh][n][64]
    u16*   k     = (u16*)(ws + 34865152);       // 4 MB
    u16*   v     = (u16*)(ws + 39059456);       // 4 MB
    u16*   vt    = (u16*)(ws + 43253760);       // 4 MB  [bh][64][n]
    u16*   ybf   = q;                           // reuse q+k (8 MB) after attn
    u16*   ctx   = (u16*)(ws + 47448064);       // 4 MB
    u16*   msg   = (u16*)(ws + 51642368);       // 4 MB

    conv_kernel<<<2688, 256, 0, stream>>>(x, wqkv, wout, w1, w2,
                                          xb, wqkvb, woutb, w1b, w2b);
    gemm_kernel<0, false, false><<<dim3(64, 12), 256, 0, stream>>>(
        xb, nullptr, wqkvb, bqkv, nullptr, qkvf, nullptr, 8192, 768, 256);
    rope_kernel<<<4096, 256, 0, stream>>>(qkvf, enc, q, k, v);
    transpose_v<<<dim3(64, 8), 256, 0, stream>>>(v, vt);
    attn_kernel<<<dim3(64, 8, 2), 256, 0, stream>>>(q, k, vt, Opart, MSpart);
    combine_kernel<<<1024, 256, 0, stream>>>(Opart, MSpart, ctx);
    gemm_kernel<1, false, false><<<dim3(64, 4), 256, 0, stream>>>(
        ctx, nullptr, woutb, bout, nullptr, nullptr, msg, 8192, 256, 256);
    gemm_kernel<0, true, false><<<dim3(64, 8), 256, 0, stream>>>(
        xb, msg, w1b, b1, nullptr, y1, nullptr, 8192, 512, 512);
    ln_gelu_kernel<<<2048, 256, 0, stream>>>(y1, lng, lnb, ybf);
    gemm_kernel<0, false, true><<<dim3(64, 4), 256, 0, stream>>>(
        ybf, nullptr, w2b, b2, x, out, nullptr, 8192, 256, 512);
}